// Round 1
// baseline (1009.091 us; speedup 1.0000x reference)
//
#include <hip/hip_runtime.h>
#include <hip/hip_bf16.h>

// Problem: Bs=2, M=32, T=1024, C=768, N=12 heads, D=64. BM = Bs*M = 64.
// x: [64*1024, 768] fp32. out same shape.
// Math simplification (see reference):
//   k = elu(x@wk.T+bk)+1 ; kr[t,n]=sum_d k ; ksum[n,d]=sum_t k
//   xk[n,c'] = sum_t kr[t,n] x[t,c']      (avoids v GEMM)
//   s[n,e]   = xk[n,:]·wv[nD+e,:] + krtot[n]*bv[nD+e]
//   u[n,c]   = sum_e s[n,e] wp[c,nD+e]    (rank-12 output)
//   q = elu(x@wq.T+bq)+1 ; z[t,n] = 1/(q[t,nHead]·ksum[n]+eps)
//   out[t,c] = bp[c] + sum_n z[t,n] u[n,c]

typedef float f32x4 __attribute__((ext_vector_type(4)));
typedef short s16x4 __attribute__((ext_vector_type(4)));
typedef short s16x8 __attribute__((ext_vector_type(8)));

__device__ __forceinline__ short f2bf(float f) {
    unsigned u = __builtin_bit_cast(unsigned, f);
    u = (u + 0x7fffu + ((u >> 16) & 1u)) >> 16;   // RNE
    return (short)u;
}

// workspace layout (float offsets)
#define WS_KSUM 0u           // 64*768
#define WS_XK   49152u       // 64*12*768
#define WS_KR   638976u      // 64*1024*12
#define WS_Z    1425408u     // 64*1024*12
#define WS_U    2211840u     // 64*12*768
// total 2801664 floats = 11.2 MB

// ---------------------------------------------------------------------------
// Fused activation GEMM: y = elu(x @ w.T + b) + 1 over a 128x128 tile.
// MODE 0 (k): atomicAdd column sums into ksum[bm][col]; write row sums
//             (per head) into aux = kr[bm][t][12].
// MODE 1 (q): write aux = z[bm][t][12] = 1/(q·ksum + eps).
// LDS stores bf16 tiles in MFMA-fragment-permuted K order so each lane's
// 8-element fragment is a single 16B ds_read:
//   element with k = g*4 + i + 16*h  stored at  p = g*8 + h*4 + i.
// ---------------------------------------------------------------------------
template<int MODE>
__global__ __launch_bounds__(256, 2)
void gemm_act_kernel(const float* __restrict__ x, const float* __restrict__ w,
                     const float* __restrict__ bias, float* __restrict__ ksum,
                     float* __restrict__ aux)
{
    __shared__ alignas(16) short As[128][40];   // stride 40 shorts = 80B (16B-aligned rows, 2-way banks)
    __shared__ alignas(16) short Bs[128][40];

    const int ct = blockIdx.x % 6;      // col tile (128 cols = heads 2ct, 2ct+1)
    const int rt = blockIdx.x / 6;      // row tile
    const int bm = rt >> 3;
    const int t0 = (rt & 7) << 7;
    const int tid = threadIdx.x;
    const int lane = tid & 63;
    const int wid = tid >> 6;
    const int wm = wid >> 1;            // wave row half
    const int wn = wid & 1;             // wave col half

    f32x4 acc[4][4];
#pragma unroll
    for (int m = 0; m < 4; ++m)
#pragma unroll
        for (int n = 0; n < 4; ++n)
            acc[m][n] = f32x4{0.f, 0.f, 0.f, 0.f};

    // staging: thread -> (row = srow + 32r, k-quad kq), permuted LDS pos p
    const int srow = tid >> 3;
    const int kq   = (tid & 7) << 2;
    const int p    = ((kq >> 2) & 3) * 8 + (kq >> 4) * 4;

    const float* xp = x + ((long)bm * 1024 + t0) * 768 + kq;
    const float* wp_ = w + (long)(ct * 128) * 768 + kq;

    for (int k0 = 0; k0 < 768; k0 += 32) {
#pragma unroll
        for (int r = 0; r < 4; ++r) {
            const int row = srow + r * 32;
            f32x4 a4 = *(const f32x4*)(xp + (long)row * 768 + k0);
            f32x4 b4 = *(const f32x4*)(wp_ + (long)row * 768 + k0);
            s16x4 av, bv;
            av[0] = f2bf(a4[0]); av[1] = f2bf(a4[1]); av[2] = f2bf(a4[2]); av[3] = f2bf(a4[3]);
            bv[0] = f2bf(b4[0]); bv[1] = f2bf(b4[1]); bv[2] = f2bf(b4[2]); bv[3] = f2bf(b4[3]);
            *(s16x4*)&As[row][p] = av;
            *(s16x4*)&Bs[row][p] = bv;
        }
        __syncthreads();
        const int g8 = (lane >> 4) << 3;
        const int fr = lane & 15;
        s16x8 af[4], bf8[4];
#pragma unroll
        for (int m = 0; m < 4; ++m)
            af[m] = *(const s16x8*)&As[wm * 64 + m * 16 + fr][g8];
#pragma unroll
        for (int n = 0; n < 4; ++n)
            bf8[n] = *(const s16x8*)&Bs[wn * 64 + n * 16 + fr][g8];
#pragma unroll
        for (int m = 0; m < 4; ++m)
#pragma unroll
            for (int n = 0; n < 4; ++n)
                acc[m][n] = __builtin_amdgcn_mfma_f32_16x16x32_bf16(af[m], bf8[n], acc[m][n], 0, 0, 0);
        __syncthreads();
    }

    // epilogue: D frag layout col = lane&15 (+n*16+wn*64+ct*128),
    //           row = (lane>>4)*4 + j (+m*16+wm*64+t0)
    const int fr = lane & 15;
    const int head = ct * 2 + wn;

    if (MODE == 0) {
        float rowsum[4][4] = {};
#pragma unroll
        for (int n = 0; n < 4; ++n) {
            const int colg = ct * 128 + wn * 64 + n * 16 + fr;
            const float bkv = bias[colg];
            float colsum = 0.f;
#pragma unroll
            for (int m = 0; m < 4; ++m)
#pragma unroll
                for (int j = 0; j < 4; ++j) {
                    float v = acc[m][n][j] + bkv;
                    float kv = v > 0.f ? v + 1.f : __expf(v);   // elu(v)+1
                    colsum += kv;
                    rowsum[m][j] += kv;
                }
            colsum += __shfl_xor(colsum, 16);
            colsum += __shfl_xor(colsum, 32);
            if (lane < 16) atomicAdd(&ksum[(long)bm * 768 + colg], colsum);
        }
#pragma unroll
        for (int m = 0; m < 4; ++m)
#pragma unroll
            for (int j = 0; j < 4; ++j) {
                float r = rowsum[m][j];
                r += __shfl_xor(r, 1); r += __shfl_xor(r, 2);
                r += __shfl_xor(r, 4); r += __shfl_xor(r, 8);
                if (fr == 0) {
                    const int t = t0 + wm * 64 + m * 16 + (lane >> 4) * 4 + j;
                    aux[((long)bm * 1024 + t) * 12 + head] = r;
                }
            }
    } else {
        float zdot[4][4] = {};
#pragma unroll
        for (int n = 0; n < 4; ++n) {
            const int colg = ct * 128 + wn * 64 + n * 16 + fr;
            const float bqv = bias[colg];
            const float ksv = ksum[(long)bm * 768 + colg];
#pragma unroll
            for (int m = 0; m < 4; ++m)
#pragma unroll
                for (int j = 0; j < 4; ++j) {
                    float v = acc[m][n][j] + bqv;
                    float qv = v > 0.f ? v + 1.f : __expf(v);
                    zdot[m][j] += qv * ksv;
                }
        }
#pragma unroll
        for (int m = 0; m < 4; ++m)
#pragma unroll
            for (int j = 0; j < 4; ++j) {
                float r = zdot[m][j];
                r += __shfl_xor(r, 1); r += __shfl_xor(r, 2);
                r += __shfl_xor(r, 4); r += __shfl_xor(r, 8);
                if (fr == 0) {
                    const int t = t0 + wm * 64 + m * 16 + (lane >> 4) * 4 + j;
                    aux[((long)bm * 1024 + t) * 12 + head] = 1.f / (r + 1e-6f);
                }
            }
    }
}

// ---------------------------------------------------------------------------
// xk[bm][n][c'] += sum_t kr[bm][t][n] * x[bm][t][c']   (atomic over t-chunks)
// ---------------------------------------------------------------------------
__global__ __launch_bounds__(256)
void xk_kernel(const float* __restrict__ x, const float* __restrict__ kr,
               float* __restrict__ xk)
{
    __shared__ float krs[128][12];
    const int bm = blockIdx.x >> 3;
    const int t0 = (blockIdx.x & 7) << 7;
    const int tid = threadIdx.x;

    float* krsf = &krs[0][0];
    for (int i = tid; i < 1536; i += 256)
        krsf[i] = kr[((long)bm * 1024 + t0) * 12 + i];
    __syncthreads();

    float acc[3][12] = {};
    const float* xp = x + ((long)bm * 1024 + t0) * 768;
#pragma unroll 2
    for (int t = 0; t < 128; ++t) {
        const float x0 = xp[(long)t * 768 + tid];
        const float x1 = xp[(long)t * 768 + 256 + tid];
        const float x2 = xp[(long)t * 768 + 512 + tid];
#pragma unroll
        for (int n = 0; n < 12; ++n) {
            const float kv = krs[t][n];
            acc[0][n] += kv * x0;
            acc[1][n] += kv * x1;
            acc[2][n] += kv * x2;
        }
    }
#pragma unroll
    for (int i = 0; i < 3; ++i)
#pragma unroll
        for (int n = 0; n < 12; ++n)
            atomicAdd(&xk[((long)bm * 12 + n) * 768 + i * 256 + tid], acc[i][n]);
}

// ---------------------------------------------------------------------------
// s[n,e] = xk[n]·wv[nD+e] + krtot*bv[nD+e];  u[n,c] = sum_e s[n,e] wp[c,nD+e]
// one block per (bm, n)
// ---------------------------------------------------------------------------
__global__ __launch_bounds__(256)
void su_kernel(const float* __restrict__ xk, const float* __restrict__ ksum,
               const float* __restrict__ wv, const float* __restrict__ bv,
               const float* __restrict__ wp, float* __restrict__ u)
{
    __shared__ float xks[768];
    __shared__ float red[4][64];
    __shared__ float sl[64];
    __shared__ float krtot_s;
    const int bm = blockIdx.x / 12;
    const int n = blockIdx.x % 12;
    const int tid = threadIdx.x;

    for (int i = tid; i < 768; i += 256)
        xks[i] = xk[((long)bm * 12 + n) * 768 + i];
    if (tid < 64) {
        float v = ksum[(long)bm * 768 + n * 64 + tid];
        for (int m = 1; m < 64; m <<= 1) v += __shfl_xor(v, m);
        if (tid == 0) krtot_s = v;
    }
    __syncthreads();

    const int e = tid & 63, pp = tid >> 6;
    const float* wvr = wv + (long)(n * 64 + e) * 768;
    float sp = 0.f;
    for (int c = pp * 192; c < pp * 192 + 192; ++c) sp += xks[c] * wvr[c];
    red[pp][e] = sp;
    __syncthreads();
    if (tid < 64) {
        sl[tid] = red[0][tid] + red[1][tid] + red[2][tid] + red[3][tid]
                + krtot_s * bv[n * 64 + tid];
    }
    __syncthreads();

#pragma unroll
    for (int i = 0; i < 3; ++i) {
        const int c = i * 256 + tid;
        const float* wpr = wp + (long)c * 768 + n * 64;
        float uv = 0.f;
#pragma unroll
        for (int ee = 0; ee < 64; ++ee) uv += sl[ee] * wpr[ee];
        u[((long)bm * 12 + n) * 768 + c] = uv;
    }
}

// ---------------------------------------------------------------------------
// out[t,c] = bp[c] + sum_n z[t,n] * u[bm][n][c]
// one block per (bm, 16-row chunk)
// ---------------------------------------------------------------------------
__global__ __launch_bounds__(256)
void out_kernel(const float* __restrict__ z, const float* __restrict__ u,
                const float* __restrict__ bp, float* __restrict__ out)
{
    __shared__ float us[12][768];
    __shared__ float zs[16][12];
    const int bm = blockIdx.x >> 6;
    const int t0 = (blockIdx.x & 63) << 4;
    const int tid = threadIdx.x;

    float* usf = &us[0][0];
    for (int i = tid; i < 9216; i += 256)
        usf[i] = u[(long)bm * 9216 + i];
    float* zsf = &zs[0][0];
    for (int i = tid; i < 192; i += 256)
        zsf[i] = z[((long)bm * 1024 + t0) * 12 + i];
    __syncthreads();

    const float b0 = bp[tid], b1 = bp[256 + tid], b2 = bp[512 + tid];
    for (int r = 0; r < 16; ++r) {
        float zr[12];
#pragma unroll
        for (int nn = 0; nn < 12; ++nn) zr[nn] = zs[r][nn];
        float v0 = b0, v1 = b1, v2 = b2;
#pragma unroll
        for (int nn = 0; nn < 12; ++nn) {
            v0 += zr[nn] * us[nn][tid];
            v1 += zr[nn] * us[nn][256 + tid];
            v2 += zr[nn] * us[nn][512 + tid];
        }
        const long o = ((long)bm * 1024 + t0 + r) * 768;
        out[o + tid] = v0;
        out[o + 256 + tid] = v1;
        out[o + 512 + tid] = v2;
    }
}

// ---------------------------------------------------------------------------
extern "C" void kernel_launch(void* const* d_in, const int* in_sizes, int n_in,
                              void* d_out, int out_size, void* d_ws, size_t ws_size,
                              hipStream_t stream)
{
    const float* x  = (const float*)d_in[0];
    const float* wq = (const float*)d_in[1];
    const float* bq = (const float*)d_in[2];
    const float* wk = (const float*)d_in[3];
    const float* bk = (const float*)d_in[4];
    const float* wv = (const float*)d_in[5];
    const float* bv = (const float*)d_in[6];
    const float* wp = (const float*)d_in[7];
    const float* bp = (const float*)d_in[8];
    float* out = (float*)d_out;
    float* ws = (float*)d_ws;

    float* ksum = ws + WS_KSUM;
    float* xk   = ws + WS_XK;
    float* kr   = ws + WS_KR;
    float* z    = ws + WS_Z;
    float* u    = ws + WS_U;

    // zero the atomic targets (ksum + xk) — ws is poisoned before every call
    hipMemsetAsync(ksum, 0, (size_t)(49152 + 589824) * sizeof(float), stream);

    gemm_act_kernel<0><<<3072, 256, 0, stream>>>(x, wk, bk, ksum, kr);
    xk_kernel<<<512, 256, 0, stream>>>(x, kr, xk);
    su_kernel<<<768, 256, 0, stream>>>(xk, ksum, wv, bv, wp, u);
    gemm_act_kernel<1><<<3072, 256, 0, stream>>>(x, wq, bq, ksum, z);
    out_kernel<<<4096, 256, 0, stream>>>(z, u, bp, out);
}

// Round 2
// 737.685 us; speedup vs baseline: 1.3679x; 1.3679x over previous
//
#include <hip/hip_runtime.h>
#include <hip/hip_bf16.h>

// Problem: Bs=2, M=32, T=1024, C=768, N=12 heads, D=64. BM = Bs*M = 64.
// Math simplification (see round 0 notes):
//   k = elu(x@wk.T+bk)+1 ; kr[t,n]=sum_d k ; ksum[n,d]=sum_t k
//   xk[n,c'] = sum_t kr[t,n] x[t,c']      (avoids v GEMM)
//   s[n,e]   = xk[n,:]·wv[nD+e,:] + krtot[n]*bv[nD+e]
//   u[n,c]   = sum_e s[n,e] wp[c,nD+e]    (rank-12 output)
//   q = elu(x@wq.T+bq)+1 ; z[t,n] = 1/(q[t,nHead]·ksum[n]+eps)
//   out[t,c] = bp[c] + sum_n z[t,n] u[n,c]

typedef float f32x4 __attribute__((ext_vector_type(4)));
typedef short s16x4 __attribute__((ext_vector_type(4)));
typedef short s16x8 __attribute__((ext_vector_type(8)));

__device__ __forceinline__ short f2bf(float f) {
    unsigned u = __builtin_bit_cast(unsigned, f);
    u = (u + 0x7fffu + ((u >> 16) & 1u)) >> 16;   // RNE
    return (short)u;
}

// ---- workspace layout ----
// f32 region (float-element offsets)
#define WS_KSUM 0u           // 64*768
#define WS_XK   49152u       // 64*12*768
#define WS_KR   638976u      // 64*1024*12
#define WS_Z    1425408u     // 64*1024*12
#define WS_U    2211840u     // 64*12*768
#define WS_F32_FLOATS 2801664u
// bf16 region starts at float offset WS_F32_FLOATS
#define XB_ELEMS 50331648ull     // 64*1024*768
#define WB_ELEMS 589824ull       // 768*768
#define WS_NEED_BYTES (WS_F32_FLOATS * 4ull + (XB_ELEMS + 2ull * WB_ELEMS) * 2ull)

#define GLL16(g, l)                                                             \
    __builtin_amdgcn_global_load_lds(                                           \
        (const __attribute__((address_space(1))) unsigned int*)(g),             \
        (__attribute__((address_space(3))) unsigned int*)(l), 16, 0, 0)

// ---------------------------------------------------------------------------
// fp32 -> bf16 convert, 8 elems/thread/iter
// ---------------------------------------------------------------------------
__global__ __launch_bounds__(256)
void conv_kernel(const float* __restrict__ in, short* __restrict__ out, int n8)
{
    int i = blockIdx.x * 256 + threadIdx.x;
    const int stride = gridDim.x * 256;
    for (; i < n8; i += stride) {
        f32x4 a = ((const f32x4*)in)[2 * i];
        f32x4 b = ((const f32x4*)in)[2 * i + 1];
        s16x8 o;
        o[0] = f2bf(a[0]); o[1] = f2bf(a[1]); o[2] = f2bf(a[2]); o[3] = f2bf(a[3]);
        o[4] = f2bf(b[0]); o[5] = f2bf(b[1]); o[6] = f2bf(b[2]); o[7] = f2bf(b[3]);
        ((s16x8*)out)[i] = o;
    }
}

// ---------------------------------------------------------------------------
// m97-structure bf16 GEMM, fused activation epilogue.
// y = elu(xb @ wb.T + bias) + 1 over a 128x128 tile, BK=32, 4 waves.
// LDS: linear row-major [128][32] bf16 per tile, staged via global_load_lds
// width-16. Within-row 16B granules are XOR-swizzled (a ^= (r>>1)&3) by
// pre-swizzling the GLOBAL source address; fragment ds_read_b64s apply the
// same XOR -> balanced banks (4 dwords/bank = b64 floor).
// Fragment k-order: lane g=l>>4 holds k in {4g..4g+3} u {16+4g..16+4g+3}
// (lo/hi 8B chunks of the row) — verified correct in round 1.
// MODE 0 (k): atomic col-sums -> ksum, per-head row sums -> kr.
// MODE 1 (q): z = 1/(q·ksum + eps).
// ---------------------------------------------------------------------------
template<int MODE>
__global__ __launch_bounds__(256, 2)
void gemm_bf16_kernel(const short* __restrict__ xb, const short* __restrict__ wb,
                      const float* __restrict__ bias, float* __restrict__ ksum,
                      float* __restrict__ aux)
{
    __shared__ alignas(16) short As[128][32];
    __shared__ alignas(16) short Bsh[128][32];

    // bijective XCD swizzle: 3072 blocks, 8 XCDs -> contiguous 384-tile chunks
    const int bid = blockIdx.x;
    const int swz = (bid & 7) * 384 + (bid >> 3);
    const int ct = swz % 6;          // column tile: heads 2ct, 2ct+1
    const int rt = swz / 6;          // row tile: global rows [rt*128, +128)
    const int bm = rt >> 3;
    const int t0loc = (rt & 7) << 7;
    const int tid = threadIdx.x;
    const int lane = tid & 63;
    const int w = tid >> 6;
    const int wm = w >> 1, wn = w & 1;

    // ---- staging addresses (per-lane global src, wave-uniform LDS dst) ----
    // issue i in {0,1}: local rows [w*32+i*16, +16); lane covers row += lane>>2,
    // 16B granule a = lane&3; source granule = a ^ ((r>>1)&3)
    const int r0 = w * 32 + (lane >> 2);
    const int r1 = r0 + 16;
    const int ga = lane & 3;
    const int c0 = (ga ^ ((r0 >> 1) & 3)) << 3;  // element offset within row
    const int c1 = (ga ^ ((r1 >> 1) & 3)) << 3;
    const short* pA0 = xb + (long)(rt * 128 + r0) * 768 + c0;
    const short* pA1 = xb + (long)(rt * 128 + r1) * 768 + c1;
    const short* pB0 = wb + (long)(ct * 128 + r0) * 768 + c0;
    const short* pB1 = wb + (long)(ct * 128 + r1) * 768 + c1;
    short* ldsA0 = &As[w * 32][0];
    short* ldsA1 = &As[w * 32 + 16][0];
    short* ldsB0 = &Bsh[w * 32][0];
    short* ldsB1 = &Bsh[w * 32 + 16][0];

    // ---- fragment LDS byte offsets (loop-invariant) ----
    const int fr = lane & 15, g = lane >> 4;
    int offAlo[4], offAhi[4], offBlo[4], offBhi[4];
#pragma unroll
    for (int m = 0; m < 4; ++m) {
        const int rA = wm * 64 + m * 16 + fr;
        const int sa = (rA >> 1) & 3;
        offAlo[m] = rA * 64 + ((((g >> 1) + 0) ^ sa) << 4) + ((g & 1) << 3);
        offAhi[m] = rA * 64 + ((((g >> 1) + 2) ^ sa) << 4) + ((g & 1) << 3);
        const int rB = wn * 64 + m * 16 + fr;
        const int sb = (rB >> 1) & 3;
        offBlo[m] = rB * 64 + ((((g >> 1) + 0) ^ sb) << 4) + ((g & 1) << 3);
        offBhi[m] = rB * 64 + ((((g >> 1) + 2) ^ sb) << 4) + ((g & 1) << 3);
    }
    const char* ldsAb = (const char*)&As[0][0];
    const char* ldsBb = (const char*)&Bsh[0][0];

    f32x4 acc[4][4];
#pragma unroll
    for (int m = 0; m < 4; ++m)
#pragma unroll
        for (int n = 0; n < 4; ++n)
            acc[m][n] = f32x4{0.f, 0.f, 0.f, 0.f};

    for (int k0 = 0; k0 < 768; k0 += 32) {
        GLL16(pA0 + k0, ldsA0);
        GLL16(pA1 + k0, ldsA1);
        GLL16(pB0 + k0, ldsB0);
        GLL16(pB1 + k0, ldsB1);
        __syncthreads();
        s16x8 af[4], bfr[4];
#pragma unroll
        for (int m = 0; m < 4; ++m) {
            s16x4 lo = *(const s16x4*)(ldsAb + offAlo[m]);
            s16x4 hi = *(const s16x4*)(ldsAb + offAhi[m]);
            af[m] = __builtin_shufflevector(lo, hi, 0, 1, 2, 3, 4, 5, 6, 7);
        }
#pragma unroll
        for (int n = 0; n < 4; ++n) {
            s16x4 lo = *(const s16x4*)(ldsBb + offBlo[n]);
            s16x4 hi = *(const s16x4*)(ldsBb + offBhi[n]);
            bfr[n] = __builtin_shufflevector(lo, hi, 0, 1, 2, 3, 4, 5, 6, 7);
        }
#pragma unroll
        for (int m = 0; m < 4; ++m)
#pragma unroll
            for (int n = 0; n < 4; ++n)
                acc[m][n] = __builtin_amdgcn_mfma_f32_16x16x32_bf16(af[m], bfr[n], acc[m][n], 0, 0, 0);
        __syncthreads();
    }

    // ---- epilogue (identical math to round 1) ----
    // D frag: col = lane&15 (+n*16+wn*64+ct*128), row = (lane>>4)*4+j (+m*16+wm*64)
    const int head = ct * 2 + wn;

    if (MODE == 0) {
        float rowsum[4][4] = {};
#pragma unroll
        for (int n = 0; n < 4; ++n) {
            const int colg = ct * 128 + wn * 64 + n * 16 + fr;
            const float bkv = bias[colg];
            float colsum = 0.f;
#pragma unroll
            for (int m = 0; m < 4; ++m)
#pragma unroll
                for (int j = 0; j < 4; ++j) {
                    float v = acc[m][n][j] + bkv;
                    float kv = v > 0.f ? v + 1.f : __expf(v);   // elu(v)+1
                    colsum += kv;
                    rowsum[m][j] += kv;
                }
            colsum += __shfl_xor(colsum, 16);
            colsum += __shfl_xor(colsum, 32);
            if (lane < 16) atomicAdd(&ksum[(long)bm * 768 + colg], colsum);
        }
#pragma unroll
        for (int m = 0; m < 4; ++m)
#pragma unroll
            for (int j = 0; j < 4; ++j) {
                float r = rowsum[m][j];
                r += __shfl_xor(r, 1); r += __shfl_xor(r, 2);
                r += __shfl_xor(r, 4); r += __shfl_xor(r, 8);
                if (fr == 0) {
                    const int t = t0loc + wm * 64 + m * 16 + (lane >> 4) * 4 + j;
                    aux[((long)bm * 1024 + t) * 12 + head] = r;
                }
            }
    } else {
        float zdot[4][4] = {};
#pragma unroll
        for (int n = 0; n < 4; ++n) {
            const int colg = ct * 128 + wn * 64 + n * 16 + fr;
            const float bqv = bias[colg];
            const float ksv = ksum[(long)bm * 768 + colg];
#pragma unroll
            for (int m = 0; m < 4; ++m)
#pragma unroll
                for (int j = 0; j < 4; ++j) {
                    float v = acc[m][n][j] + bqv;
                    float qv = v > 0.f ? v + 1.f : __expf(v);
                    zdot[m][j] += qv * ksv;
                }
        }
#pragma unroll
        for (int m = 0; m < 4; ++m)
#pragma unroll
            for (int j = 0; j < 4; ++j) {
                float r = zdot[m][j];
                r += __shfl_xor(r, 1); r += __shfl_xor(r, 2);
                r += __shfl_xor(r, 4); r += __shfl_xor(r, 8);
                if (fr == 0) {
                    const int t = t0loc + wm * 64 + m * 16 + (lane >> 4) * 4 + j;
                    aux[((long)bm * 1024 + t) * 12 + head] = 1.f / (r + 1e-6f);
                }
            }
    }
}

// ---------------------------------------------------------------------------
// OLD round-1 fused fp32 GEMM — kept only as ws_size fallback path.
// ---------------------------------------------------------------------------
template<int MODE>
__global__ __launch_bounds__(256, 2)
void gemm_act_kernel(const float* __restrict__ x, const float* __restrict__ w,
                     const float* __restrict__ bias, float* __restrict__ ksum,
                     float* __restrict__ aux)
{
    __shared__ alignas(16) short As[128][40];
    __shared__ alignas(16) short Bs[128][40];

    const int ct = blockIdx.x % 6;
    const int rt = blockIdx.x / 6;
    const int bm = rt >> 3;
    const int t0 = (rt & 7) << 7;
    const int tid = threadIdx.x;
    const int lane = tid & 63;
    const int wid = tid >> 6;
    const int wm = wid >> 1;
    const int wn = wid & 1;

    f32x4 acc[4][4];
#pragma unroll
    for (int m = 0; m < 4; ++m)
#pragma unroll
        for (int n = 0; n < 4; ++n)
            acc[m][n] = f32x4{0.f, 0.f, 0.f, 0.f};

    const int srow = tid >> 3;
    const int kq   = (tid & 7) << 2;
    const int p    = ((kq >> 2) & 3) * 8 + (kq >> 4) * 4;

    const float* xp = x + ((long)bm * 1024 + t0) * 768 + kq;
    const float* wp_ = w + (long)(ct * 128) * 768 + kq;

    for (int k0 = 0; k0 < 768; k0 += 32) {
#pragma unroll
        for (int r = 0; r < 4; ++r) {
            const int row = srow + r * 32;
            f32x4 a4 = *(const f32x4*)(xp + (long)row * 768 + k0);
            f32x4 b4 = *(const f32x4*)(wp_ + (long)row * 768 + k0);
            s16x4 av, bv;
            av[0] = f2bf(a4[0]); av[1] = f2bf(a4[1]); av[2] = f2bf(a4[2]); av[3] = f2bf(a4[3]);
            bv[0] = f2bf(b4[0]); bv[1] = f2bf(b4[1]); bv[2] = f2bf(b4[2]); bv[3] = f2bf(b4[3]);
            *(s16x4*)&As[row][p] = av;
            *(s16x4*)&Bs[row][p] = bv;
        }
        __syncthreads();
        const int g8 = (lane >> 4) << 3;
        const int fr = lane & 15;
        s16x8 af[4], bf8[4];
#pragma unroll
        for (int m = 0; m < 4; ++m)
            af[m] = *(const s16x8*)&As[wm * 64 + m * 16 + fr][g8];
#pragma unroll
        for (int n = 0; n < 4; ++n)
            bf8[n] = *(const s16x8*)&Bs[wn * 64 + n * 16 + fr][g8];
#pragma unroll
        for (int m = 0; m < 4; ++m)
#pragma unroll
            for (int n = 0; n < 4; ++n)
                acc[m][n] = __builtin_amdgcn_mfma_f32_16x16x32_bf16(af[m], bf8[n], acc[m][n], 0, 0, 0);
        __syncthreads();
    }

    const int fr = lane & 15;
    const int head = ct * 2 + wn;

    if (MODE == 0) {
        float rowsum[4][4] = {};
#pragma unroll
        for (int n = 0; n < 4; ++n) {
            const int colg = ct * 128 + wn * 64 + n * 16 + fr;
            const float bkv = bias[colg];
            float colsum = 0.f;
#pragma unroll
            for (int m = 0; m < 4; ++m)
#pragma unroll
                for (int j = 0; j < 4; ++j) {
                    float v = acc[m][n][j] + bkv;
                    float kv = v > 0.f ? v + 1.f : __expf(v);
                    colsum += kv;
                    rowsum[m][j] += kv;
                }
            colsum += __shfl_xor(colsum, 16);
            colsum += __shfl_xor(colsum, 32);
            if (lane < 16) atomicAdd(&ksum[(long)bm * 768 + colg], colsum);
        }
#pragma unroll
        for (int m = 0; m < 4; ++m)
#pragma unroll
            for (int j = 0; j < 4; ++j) {
                float r = rowsum[m][j];
                r += __shfl_xor(r, 1); r += __shfl_xor(r, 2);
                r += __shfl_xor(r, 4); r += __shfl_xor(r, 8);
                if (fr == 0) {
                    const int t = t0 + wm * 64 + m * 16 + (lane >> 4) * 4 + j;
                    aux[((long)bm * 1024 + t) * 12 + head] = r;
                }
            }
    } else {
        float zdot[4][4] = {};
#pragma unroll
        for (int n = 0; n < 4; ++n) {
            const int colg = ct * 128 + wn * 64 + n * 16 + fr;
            const float bqv = bias[colg];
            const float ksv = ksum[(long)bm * 768 + colg];
#pragma unroll
            for (int m = 0; m < 4; ++m)
#pragma unroll
                for (int j = 0; j < 4; ++j) {
                    float v = acc[m][n][j] + bqv;
                    float qv = v > 0.f ? v + 1.f : __expf(v);
                    zdot[m][j] += qv * ksv;
                }
        }
#pragma unroll
        for (int m = 0; m < 4; ++m)
#pragma unroll
            for (int j = 0; j < 4; ++j) {
                float r = zdot[m][j];
                r += __shfl_xor(r, 1); r += __shfl_xor(r, 2);
                r += __shfl_xor(r, 4); r += __shfl_xor(r, 8);
                if (fr == 0) {
                    const int t = t0 + wm * 64 + m * 16 + (lane >> 4) * 4 + j;
                    aux[((long)bm * 1024 + t) * 12 + head] = 1.f / (r + 1e-6f);
                }
            }
    }
}

// ---------------------------------------------------------------------------
// xk[bm][n][c'] += sum_t kr[bm][t][n] * x[bm][t][c']
// ---------------------------------------------------------------------------
__global__ __launch_bounds__(256)
void xk_kernel(const float* __restrict__ x, const float* __restrict__ kr,
               float* __restrict__ xk)
{
    __shared__ float krs[128][12];
    const int bm = blockIdx.x >> 3;
    const int t0 = (blockIdx.x & 7) << 7;
    const int tid = threadIdx.x;

    float* krsf = &krs[0][0];
    for (int i = tid; i < 1536; i += 256)
        krsf[i] = kr[((long)bm * 1024 + t0) * 12 + i];
    __syncthreads();

    float acc[3][12] = {};
    const float* xp = x + ((long)bm * 1024 + t0) * 768;
#pragma unroll 2
    for (int t = 0; t < 128; ++t) {
        const float x0 = xp[(long)t * 768 + tid];
        const float x1 = xp[(long)t * 768 + 256 + tid];
        const float x2 = xp[(long)t * 768 + 512 + tid];
#pragma unroll
        for (int n = 0; n < 12; ++n) {
            const float kv = krs[t][n];
            acc[0][n] += kv * x0;
            acc[1][n] += kv * x1;
            acc[2][n] += kv * x2;
        }
    }
#pragma unroll
    for (int i = 0; i < 3; ++i)
#pragma unroll
        for (int n = 0; n < 12; ++n)
            atomicAdd(&xk[((long)bm * 12 + n) * 768 + i * 256 + tid], acc[i][n]);
}

// ---------------------------------------------------------------------------
// s[n,e] = xk[n]·wv[nD+e] + krtot*bv[nD+e];  u[n,c] = sum_e s[n,e] wp[c,nD+e]
// ---------------------------------------------------------------------------
__global__ __launch_bounds__(256)
void su_kernel(const float* __restrict__ xk, const float* __restrict__ ksum,
               const float* __restrict__ wv, const float* __restrict__ bv,
               const float* __restrict__ wp, float* __restrict__ u)
{
    __shared__ float xks[768];
    __shared__ float red[4][64];
    __shared__ float sl[64];
    __shared__ float krtot_s;
    const int bm = blockIdx.x / 12;
    const int n = blockIdx.x % 12;
    const int tid = threadIdx.x;

    for (int i = tid; i < 768; i += 256)
        xks[i] = xk[((long)bm * 12 + n) * 768 + i];
    if (tid < 64) {
        float v = ksum[(long)bm * 768 + n * 64 + tid];
        for (int m = 1; m < 64; m <<= 1) v += __shfl_xor(v, m);
        if (tid == 0) krtot_s = v;
    }
    __syncthreads();

    const int e = tid & 63, pp = tid >> 6;
    const float* wvr = wv + (long)(n * 64 + e) * 768;
    float sp = 0.f;
    for (int c = pp * 192; c < pp * 192 + 192; ++c) sp += xks[c] * wvr[c];
    red[pp][e] = sp;
    __syncthreads();
    if (tid < 64) {
        sl[tid] = red[0][tid] + red[1][tid] + red[2][tid] + red[3][tid]
                + krtot_s * bv[n * 64 + tid];
    }
    __syncthreads();

#pragma unroll
    for (int i = 0; i < 3; ++i) {
        const int c = i * 256 + tid;
        const float* wpr = wp + (long)c * 768 + n * 64;
        float uv = 0.f;
#pragma unroll
        for (int ee = 0; ee < 64; ++ee) uv += sl[ee] * wpr[ee];
        u[((long)bm * 12 + n) * 768 + c] = uv;
    }
}

// ---------------------------------------------------------------------------
// out[t,c] = bp[c] + sum_n z[t,n] * u[bm][n][c]
// ---------------------------------------------------------------------------
__global__ __launch_bounds__(256)
void out_kernel(const float* __restrict__ z, const float* __restrict__ u,
                const float* __restrict__ bp, float* __restrict__ out)
{
    __shared__ float us[12][768];
    __shared__ float zs[16][12];
    const int bm = blockIdx.x >> 6;
    const int t0 = (blockIdx.x & 63) << 4;
    const int tid = threadIdx.x;

    float* usf = &us[0][0];
    for (int i = tid; i < 9216; i += 256)
        usf[i] = u[(long)bm * 9216 + i];
    float* zsf = &zs[0][0];
    for (int i = tid; i < 192; i += 256)
        zsf[i] = z[((long)bm * 1024 + t0) * 12 + i];
    __syncthreads();

    const float b0 = bp[tid], b1 = bp[256 + tid], b2 = bp[512 + tid];
    for (int r = 0; r < 16; ++r) {
        float zr[12];
#pragma unroll
        for (int nn = 0; nn < 12; ++nn) zr[nn] = zs[r][nn];
        float v0 = b0, v1 = b1, v2 = b2;
#pragma unroll
        for (int nn = 0; nn < 12; ++nn) {
            v0 += zr[nn] * us[nn][tid];
            v1 += zr[nn] * us[nn][256 + tid];
            v2 += zr[nn] * us[nn][512 + tid];
        }
        const long o = ((long)bm * 1024 + t0 + r) * 768;
        out[o + tid] = v0;
        out[o + 256 + tid] = v1;
        out[o + 512 + tid] = v2;
    }
}

// ---------------------------------------------------------------------------
extern "C" void kernel_launch(void* const* d_in, const int* in_sizes, int n_in,
                              void* d_out, int out_size, void* d_ws, size_t ws_size,
                              hipStream_t stream)
{
    const float* x  = (const float*)d_in[0];
    const float* wq = (const float*)d_in[1];
    const float* bq = (const float*)d_in[2];
    const float* wk = (const float*)d_in[3];
    const float* bk = (const float*)d_in[4];
    const float* wv = (const float*)d_in[5];
    const float* bv = (const float*)d_in[6];
    const float* wp = (const float*)d_in[7];
    const float* bp = (const float*)d_in[8];
    float* out = (float*)d_out;
    float* ws = (float*)d_ws;

    float* ksum = ws + WS_KSUM;
    float* xk   = ws + WS_XK;
    float* kr   = ws + WS_KR;
    float* z    = ws + WS_Z;
    float* u    = ws + WS_U;

    // zero the atomic targets (ksum + xk)
    hipMemsetAsync(ksum, 0, (size_t)(49152 + 589824) * sizeof(float), stream);

    if (ws_size >= WS_NEED_BYTES) {
        short* xbb = (short*)(ws + WS_F32_FLOATS);
        short* wkb = xbb + XB_ELEMS;
        short* wqb = wkb + WB_ELEMS;

        conv_kernel<<<2048, 256, 0, stream>>>(x, xbb, 6291456);
        conv_kernel<<<288, 256, 0, stream>>>(wk, wkb, 73728);
        conv_kernel<<<288, 256, 0, stream>>>(wq, wqb, 73728);

        gemm_bf16_kernel<0><<<3072, 256, 0, stream>>>(xbb, wkb, bk, ksum, kr);
        xk_kernel<<<512, 256, 0, stream>>>(x, kr, xk);
        su_kernel<<<768, 256, 0, stream>>>(xk, ksum, wv, bv, wp, u);
        gemm_bf16_kernel<1><<<3072, 256, 0, stream>>>(xbb, wqb, bq, ksum, z);
        out_kernel<<<4096, 256, 0, stream>>>(z, u, bp, out);
    } else {
        gemm_act_kernel<0><<<3072, 256, 0, stream>>>(x, wk, bk, ksum, kr);
        xk_kernel<<<512, 256, 0, stream>>>(x, kr, xk);
        su_kernel<<<768, 256, 0, stream>>>(xk, ksum, wv, bv, wp, u);
        gemm_act_kernel<1><<<3072, 256, 0, stream>>>(x, wq, bq, ksum, z);
        out_kernel<<<4096, 256, 0, stream>>>(z, u, bp, out);
    }
}